// Round 8
// baseline (1434.119 us; speedup 1.0000x reference)
//
#include <hip/hip_runtime.h>
#include <math.h>

#define H 64
#define VOCABN 64
#define LSEQ 2048
#define LN_EPS 1e-5f

// ---------- generic DPP add helper ----------
template <int CTRL>
__device__ __forceinline__ float dpp_add(float x) {
  return x + __int_as_float(__builtin_amdgcn_update_dpp(
      0, __float_as_int(x), CTRL, 0xF, 0xF, true));
}

// all-lane sum with broadcast result (tables / readout only)
__device__ __forceinline__ float wave_allsum(float x) {
  x = dpp_add<0xB1>(x);   // quad_perm [1,0,3,2]
  x = dpp_add<0x4E>(x);   // quad_perm [2,3,0,1]
  x = dpp_add<0x141>(x);  // row_half_mirror
  x = dpp_add<0x140>(x);  // row_mirror
  x += __shfl_xor(x, 16, 64);
  x += __shfl_xor(x, 32, 64);
  return x;
}

// all-VALU wave64 reduction of nonneg terms: lane 63 holds the total; every
// lane holds a PARTIAL sum (subset of terms), so with X>=0:
//   __any(partial >= X) <=> total >= X
__device__ __forceinline__ float reduce_to_lane63(float x) {
  x = dpp_add<0x111>(x);  // row_shr:1
  x = dpp_add<0x112>(x);  // row_shr:2
  x = dpp_add<0x114>(x);  // row_shr:4
  x = dpp_add<0x118>(x);  // row_shr:8
  x = dpp_add<0x142>(x);  // row_bcast:15
  x = dpp_add<0x143>(x);  // row_bcast:31
  return x;
}

// ---------------- Kernel A: per-token tables (verbatim round 7, passed) ----------------
__global__ __launch_bounds__(64) void tables_kernel(
    const float* __restrict__ embed, const float* __restrict__ W1, const float* __restrict__ b1,
    const float* __restrict__ W2, const float* __restrict__ b2,
    const float* __restrict__ ln_g, const float* __restrict__ ln_b,
    const float* __restrict__ Wk, const float* __restrict__ Wv,
    float* __restrict__ Htab, float* __restrict__ Ktab, float* __restrict__ Vtab,
    float* __restrict__ nvtab)
{
  __shared__ float hs[H];
  __shared__ float ff1[2 * H];
  __shared__ float lns[H];
  const int c = blockIdx.x;
  const int i = threadIdx.x;

  float e = embed[c * H + i];
  hs[i] = e;
  __syncthreads();

  float r1 = b1[i], r2 = b1[i + H];
  for (int j = 0; j < H; ++j) {
    float hj = hs[j];
    r1 = fmaf(W1[i * H + j], hj, r1);
    r2 = fmaf(W1[(i + H) * H + j], hj, r2);
  }
  ff1[i]     = fmaxf(r1, 0.f);
  ff1[i + H] = fmaxf(r2, 0.f);
  __syncthreads();

  float o = b2[i];
  for (int m = 0; m < 2 * H; ++m) o = fmaf(W2[i * 2 * H + m], ff1[m], o);
  float y = e + o;

  float mu  = wave_allsum(y) * (1.f / H);
  float d   = y - mu;
  float var = wave_allsum(d * d) * (1.f / H);
  float ln  = d * (1.f / sqrtf(var + LN_EPS)) * ln_g[i] + ln_b[i];
  lns[i] = ln;
  __syncthreads();
  Htab[c * H + i] = ln;

  float k = 0.f, v = 0.f;
  for (int j = 0; j < H; ++j) {
    float lj = lns[j];
    k = fmaf(Wk[i * H + j], lj, k);
    v = fmaf(Wv[i * H + j], lj, v);
  }
  float nk = sqrtf(wave_allsum(k * k));
  Ktab[c * H + i] = k / fmaxf(nk, 1e-12f);
  Vtab[c * H + i] = v;
  float nv = sqrtf(wave_allsum(v * v));
  if (i == 0) nvtab[c] = 0.4f * nv;   // gate threshold (round-3 semantics)
}

// ---------------- Kernel B: screened residual scan + fused readout ----------------
// One wave per batch element. M rows in registers (lane i = row i).
// R[c] ~ v_c - M khat_c cached in LDS (drift <= ~1e-4 rel) is ONLY a reject
// screen. Screen fires -> fresh recompute (verbatim round-3 math; bitwise
// round-3 gates & deltas -> bitwise round-3 M). Accept -> Gram-based R update
// (Gram computed here in LDS; NO extra workspace beyond round-3 layout).
__global__ __launch_bounds__(64, 1) void scan_kernel(
    const int* __restrict__ x, const float* __restrict__ Htab,
    const float* __restrict__ Ktab, const float* __restrict__ Vtab,
    const float* __restrict__ nvtab,
    const float* __restrict__ Wq, const float* __restrict__ Wr,
    const float* __restrict__ alpha, const float* __restrict__ Wout,
    const float* __restrict__ bout, float* __restrict__ out)
{
  __shared__ float4 Kl4[VOCABN * H / 4];   // khat; reused as M_N in readout
  __shared__ float4 Vl4[VOCABN * H / 4];   // v;    reused as M_T in readout
  __shared__ float4 Rl4[VOCABN * H / 4];   // residual cache [c][i]
  __shared__ float4 Gl4[VOCABN * H / 4];   // Gram [c][cc]
  __shared__ int4   xl4[LSEQ / 4];
  __shared__ float  thl[VOCABN];           // 0.4*||v||
  __shared__ float  scrl[VOCABN];          // 0.995*(0.4*||v||)^2
  __shared__ float  hbuf[H];
  __shared__ float  qbuf[H];
  __shared__ float  mbuf[H];
  float* Kl = (float*)Kl4;
  float* Vl = (float*)Vl4;
  float* Rl = (float*)Rl4;
  float* Gl = (float*)Gl4;
  int*   xl = (int*)xl4;

  const int b = blockIdx.x;
  const int lane = threadIdx.x;

  // ---- stage tables + token row into LDS ----
  {
    const float4* Kg = (const float4*)Ktab;
    const float4* Vg = (const float4*)Vtab;
    for (int q = lane; q < VOCABN * H / 4; q += 64) {
      float4 vq = Vg[q];
      Kl4[q] = Kg[q]; Vl4[q] = vq; Rl4[q] = vq;   // R init = v (M = 0)
    }
    const int4* xg = (const int4*)(x + b * LSEQ);
    for (int q = lane; q < LSEQ / 4; q += 64) xl4[q] = xg[q];
    float thv = nvtab[lane];
    thl[lane]  = thv;
    scrl[lane] = thv * thv * 0.995f;
  }
  __syncthreads();

  // ---- Gram in LDS: G[c2][lane] = khat_lane . khat_c2 (one-time, ~8 us) ----
  {
    float4 kr[16];                         // own khat row (lane = token)
#pragma unroll
    for (int q = 0; q < 16; ++q) kr[q] = Kl4[lane * 16 + q];
    for (int c2 = 0; c2 < VOCABN; ++c2) {
      const float4* kp2 = (const float4*)(Kl + c2 * H);
      float a0 = 0.f, a1 = 0.f, a2 = 0.f, a3 = 0.f;
#pragma unroll
      for (int q = 0; q < 16; ++q) {
        float4 kq = kp2[q];
        a0 = fmaf(kr[q].x, kq.x, a0);
        a1 = fmaf(kr[q].y, kq.y, a1);
        a2 = fmaf(kr[q].z, kq.z, a2);
        a3 = fmaf(kr[q].w, kq.w, a3);
      }
      Gl[c2 * H + lane] = (a0 + a1) + (a2 + a3);
    }
  }
  __syncthreads();

  float4 M4[16];
#pragma unroll
  for (int q = 0; q < 16; ++q) M4[q] = make_float4(0.f, 0.f, 0.f, 0.f);

  int   c   = xl[0];
  float rv  = Rl[c * H + lane];
  float thr = thl[c];
  float scr = scrl[c];

  for (int t = 0; t < LSEQ; ++t) {
    const int cn  = (t + 1 < LSEQ) ? xl[t + 1] : 0;
    float rvn  = Rl[cn * H + lane];        // speculative prefetch
    float thrn = thl[cn];
    float scrn = scrl[cn];

    float nd2 = reduce_to_lane63(rv * rv);
    if (__any(nd2 >= scr)) {
      // potential accept: fresh recompute (verbatim round-3 STEPC math)
      const float4* kp = (const float4*)(Kl + c * H);
      float a0 = 0.f, a1 = 0.f, a2 = 0.f, a3 = 0.f;
#pragma unroll
      for (int q = 0; q < 16; ++q) {
        float4 kq = kp[q];
        a0 = fmaf(M4[q].x, kq.x, a0);
        a1 = fmaf(M4[q].y, kq.y, a1);
        a2 = fmaf(M4[q].z, kq.z, a2);
        a3 = fmaf(M4[q].w, kq.w, a3);
      }
      float pred  = (a0 + a1) + (a2 + a3);
      float fresh = Vl[c * H + lane] - pred;
      Rl[c * H + lane] = fresh;            // de-drift this row
      float nf2 = reduce_to_lane63(fresh * fresh);
      float nds = sqrtf(__int_as_float(__builtin_amdgcn_readlane(__float_as_int(nf2), 63)));
      float thu = __int_as_float(__builtin_amdgcn_readfirstlane(__float_as_int(thr)));
      if (nds > thu) {
        const float delta = fresh;
        // R[cc] -= G[c][cc] * delta  (includes cc==c: fresh*(1-G[c,c]) ~ 0)
#pragma unroll 16
        for (int cc = 0; cc < VOCABN; ++cc) {
          float g = Gl[c * H + cc];        // broadcast
          Rl[cc * H + lane] = fmaf(-g, delta, Rl[cc * H + lane]);
        }
        // M row i += delta[i] * khat_c
#pragma unroll
        for (int q = 0; q < 16; ++q) {
          float4 kq = kp[q];
          M4[q].x = fmaf(delta, kq.x, M4[q].x);
          M4[q].y = fmaf(delta, kq.y, M4[q].y);
          M4[q].z = fmaf(delta, kq.z, M4[q].z);
          M4[q].w = fmaf(delta, kq.w, M4[q].w);
        }
      }
      rvn = Rl[cn * H + lane];             // reload after LDS writes
    }
    rv = rvn; thr = thrn; scr = scrn; c = cn;
  }

  // ---------------- fused readout (verbatim round 7) ----------------
  __syncthreads();
  // M row-major into Kl (M_N[i*H+j]), transposed into Vl (M_T[j*H+i])
  {
    float4* MN = (float4*)(Kl + lane * H);
#pragma unroll
    for (int q = 0; q < 16; ++q) MN[q] = M4[q];
#pragma unroll
    for (int q = 0; q < 16; ++q) {
      Vl[(4 * q + 0) * H + lane] = M4[q].x;
      Vl[(4 * q + 1) * H + lane] = M4[q].y;
      Vl[(4 * q + 2) * H + lane] = M4[q].z;
      Vl[(4 * q + 3) * H + lane] = M4[q].w;
    }
  }
  __syncthreads();

  const int clast = xl[LSEQ - 1];
  hbuf[lane] = Htab[clast * H + lane];
  __syncthreads();

  float qi = 0.f;
  for (int j = 0; j < H; ++j) qi = fmaf(Wq[lane * H + j], hbuf[j], qi);
  qbuf[lane] = qi;
  __syncthreads();

  float qri = 0.f;
  for (int j = 0; j < H; ++j) qri = fmaf(Wr[lane * H + j], qbuf[j], qri);

  // slot norms^2: slot s = column s of M; lane s reads M_N[i*H+s] (conflict-free)
  float n2 = 0.f;
  for (int i2 = 0; i2 < H; ++i2) { float m = Kl[i2 * H + lane]; n2 = fmaf(m, m, n2); }

  // top-8 slots by norm (ties -> smaller index, matching lax.top_k)
  const int KS = 8;
  int idxs[KS];
  float nloc = n2;
#pragma unroll
  for (int k = 0; k < KS; ++k) {
    float v = nloc; int idx = lane;
#pragma unroll
    for (int s = 1; s < 64; s <<= 1) {
      float ov = __shfl_xor(v, s, 64);
      int   oi = __shfl_xor(idx, s, 64);
      if (ov > v || (ov == v && oi < idx)) { v = ov; idx = oi; }
    }
    idxs[k] = idx;
    if (lane == idx) nloc = -1.f;
  }

  // logits + selected slot values (sel[k][lane] = M_T[idx_k*H + lane])
  float sel[KS], lg[KS];
#pragma unroll
  for (int k = 0; k < KS; ++k) {
    float s = Vl[idxs[k] * H + lane];
    sel[k] = s;
    lg[k] = wave_allsum(s * qri) * 0.125f;   // / sqrt(64)
  }
  float lmax = lg[0];
#pragma unroll
  for (int k = 1; k < KS; ++k) lmax = fmaxf(lmax, lg[k]);
  float esum = 0.f, retro = 0.f;
#pragma unroll
  for (int k = 0; k < KS; ++k) {
    float e = expf(lg[k] - lmax);
    esum += e;
    retro = fmaf(e, sel[k], retro);
  }
  retro /= esum;

  // m_ctx = M q  (M rows still in registers; q broadcast from LDS)
  float mc = 0.f;
#pragma unroll
  for (int q2 = 0; q2 < 16; ++q2) {
    mc = fmaf(M4[q2].x, qbuf[4 * q2 + 0], mc);
    mc = fmaf(M4[q2].y, qbuf[4 * q2 + 1], mc);
    mc = fmaf(M4[q2].z, qbuf[4 * q2 + 2], mc);
    mc = fmaf(M4[q2].w, qbuf[4 * q2 + 3], mc);
  }

  float a = 1.f / (1.f + expf(-alpha[0]));
  float mixed = fmaxf(fmaf(a, retro, (1.f - a) * mc), 0.f);
  mbuf[lane] = mixed;
  __syncthreads();

  float oo = bout[lane];
  for (int i2 = 0; i2 < H; ++i2) oo = fmaf(Wout[lane * H + i2], mbuf[i2], oo);
  out[b * VOCABN + lane] = oo;
}

extern "C" void kernel_launch(void* const* d_in, const int* in_sizes, int n_in,
                              void* d_out, int out_size, void* d_ws, size_t ws_size,
                              hipStream_t stream) {
  const int*   x     = (const int*)d_in[0];
  const float* embed = (const float*)d_in[1];
  const float* W1    = (const float*)d_in[2];
  const float* b1    = (const float*)d_in[3];
  const float* W2    = (const float*)d_in[4];
  const float* b2    = (const float*)d_in[5];
  const float* ln_g  = (const float*)d_in[6];
  const float* ln_b  = (const float*)d_in[7];
  const float* Wk    = (const float*)d_in[8];
  const float* Wv    = (const float*)d_in[9];
  const float* Wq    = (const float*)d_in[10];
  const float* Wr    = (const float*)d_in[11];
  const float* alpha = (const float*)d_in[12];
  const float* Wout  = (const float*)d_in[13];
  const float* bout  = (const float*)d_in[14];
  float* out = (float*)d_out;

  const int B = in_sizes[0] / LSEQ;

  float* ws    = (float*)d_ws;
  float* Htab  = ws;          // 4096
  float* Ktab  = ws + 4096;   // 4096
  float* Vtab  = ws + 8192;   // 4096
  float* nvtab = ws + 12288;  // 64   (round-3 proven layout; no Gtab in ws)

  tables_kernel<<<VOCABN, 64, 0, stream>>>(embed, W1, b1, W2, b2, ln_g, ln_b,
                                           Wk, Wv, Htab, Ktab, Vtab, nvtab);
  scan_kernel<<<B, 64, 0, stream>>>(x, Htab, Ktab, Vtab, nvtab,
                                    Wq, Wr, alpha, Wout, bout, out);
}

// Round 9
// 1112.192 us; speedup vs baseline: 1.2895x; 1.2895x over previous
//
#include <hip/hip_runtime.h>
#include <math.h>

#define H 64
#define VOCABN 64
#define LSEQ 2048
#define LN_EPS 1e-5f

// ---------- generic DPP add helper ----------
template <int CTRL>
__device__ __forceinline__ float dpp_add(float x) {
  return x + __int_as_float(__builtin_amdgcn_update_dpp(
      0, __float_as_int(x), CTRL, 0xF, 0xF, true));
}

// all-lane sum with broadcast result (tables / readout only)
__device__ __forceinline__ float wave_allsum(float x) {
  x = dpp_add<0xB1>(x);   // quad_perm [1,0,3,2]
  x = dpp_add<0x4E>(x);   // quad_perm [2,3,0,1]
  x = dpp_add<0x141>(x);  // row_half_mirror
  x = dpp_add<0x140>(x);  // row_mirror
  x += __shfl_xor(x, 16, 64);
  x += __shfl_xor(x, 32, 64);
  return x;
}

// all-VALU wave64 reduction: lane 63 holds the total (round-3/6/7 validated)
__device__ __forceinline__ float reduce_to_lane63(float x) {
  x = dpp_add<0x111>(x);  // row_shr:1
  x = dpp_add<0x112>(x);  // row_shr:2
  x = dpp_add<0x114>(x);  // row_shr:4
  x = dpp_add<0x118>(x);  // row_shr:8
  x = dpp_add<0x142>(x);  // row_bcast:15
  x = dpp_add<0x143>(x);  // row_bcast:31
  return x;
}

// wave-uniform extraction of register-file row c (c must be SGPR-uniform)
__device__ __forceinline__ float extract_rq(const float4* Rq, int c) {
  float4 t;
  switch (c >> 2) {
    case 0:  t = Rq[0];  break;  case 1:  t = Rq[1];  break;
    case 2:  t = Rq[2];  break;  case 3:  t = Rq[3];  break;
    case 4:  t = Rq[4];  break;  case 5:  t = Rq[5];  break;
    case 6:  t = Rq[6];  break;  case 7:  t = Rq[7];  break;
    case 8:  t = Rq[8];  break;  case 9:  t = Rq[9];  break;
    case 10: t = Rq[10]; break;  case 11: t = Rq[11]; break;
    case 12: t = Rq[12]; break;  case 13: t = Rq[13]; break;
    case 14: t = Rq[14]; break;  default: t = Rq[15]; break;
  }
  switch (c & 3) {
    case 0: return t.x; case 1: return t.y; case 2: return t.z; default: return t.w;
  }
}

// ---------------- Kernel A: per-token tables (verbatim rounds 7/8, passed) ----------------
__global__ __launch_bounds__(64) void tables_kernel(
    const float* __restrict__ embed, const float* __restrict__ W1, const float* __restrict__ b1,
    const float* __restrict__ W2, const float* __restrict__ b2,
    const float* __restrict__ ln_g, const float* __restrict__ ln_b,
    const float* __restrict__ Wk, const float* __restrict__ Wv,
    float* __restrict__ Htab, float* __restrict__ Ktab, float* __restrict__ Vtab,
    float* __restrict__ nvtab)
{
  __shared__ float hs[H];
  __shared__ float ff1[2 * H];
  __shared__ float lns[H];
  const int c = blockIdx.x;
  const int i = threadIdx.x;

  float e = embed[c * H + i];
  hs[i] = e;
  __syncthreads();

  float r1 = b1[i], r2 = b1[i + H];
  for (int j = 0; j < H; ++j) {
    float hj = hs[j];
    r1 = fmaf(W1[i * H + j], hj, r1);
    r2 = fmaf(W1[(i + H) * H + j], hj, r2);
  }
  ff1[i]     = fmaxf(r1, 0.f);
  ff1[i + H] = fmaxf(r2, 0.f);
  __syncthreads();

  float o = b2[i];
  for (int m = 0; m < 2 * H; ++m) o = fmaf(W2[i * 2 * H + m], ff1[m], o);
  float y = e + o;

  float mu  = wave_allsum(y) * (1.f / H);
  float d   = y - mu;
  float var = wave_allsum(d * d) * (1.f / H);
  float ln  = d * (1.f / sqrtf(var + LN_EPS)) * ln_g[i] + ln_b[i];
  lns[i] = ln;
  __syncthreads();
  Htab[c * H + i] = ln;

  float k = 0.f, v = 0.f;
  for (int j = 0; j < H; ++j) {
    float lj = lns[j];
    k = fmaf(Wk[i * H + j], lj, k);
    v = fmaf(Wv[i * H + j], lj, v);
  }
  float nk = sqrtf(wave_allsum(k * k));
  Ktab[c * H + i] = k / fmaxf(nk, 1e-12f);
  Vtab[c * H + i] = v;
  float nv = sqrtf(wave_allsum(v * v));
  if (i == 0) nvtab[c] = 0.4f * nv;   // gate threshold (round-3 semantics, sqrt domain)
}

// ---------------- Kernel B: register-residual delta scan + fused readout ----------------
// One wave per batch element. Lane i holds R[c][i] for ALL 64 tokens (Rq, 64 VGPR)
// and M row i (M4, 64 VGPR). Per step: switch-extract rv + DPP norm + sqrt gate
// (round-3 compare semantics — the squared-compare was the rounds-4/5 bug).
// Per accept: 32 broadcast b128 LDS reads (Gram row + khat row) + 128 register FMAs.
// Drift safety: round4==round5 proved incremental-R deltas/gates match fresh ones.
__global__ __launch_bounds__(64, 1) void scan_kernel(
    const int* __restrict__ x, const float* __restrict__ Htab,
    const float* __restrict__ Ktab, const float* __restrict__ Vtab,
    const float* __restrict__ nvtab,
    const float* __restrict__ Wq, const float* __restrict__ Wr,
    const float* __restrict__ alpha, const float* __restrict__ Wout,
    const float* __restrict__ bout, float* __restrict__ out)
{
  __shared__ float4 Kl4[VOCABN * H / 4];   // khat; reused as M_N in readout
  __shared__ float4 Vl4[VOCABN * H / 4];   // v;    reused as M_T in readout
  __shared__ float4 Gl4[VOCABN * H / 4];   // Gram [c][cc]
  __shared__ int4   xl4[LSEQ / 4];
  __shared__ float  thl[VOCABN];           // 0.4*||v||
  __shared__ float  hbuf[H];
  __shared__ float  qbuf[H];
  __shared__ float  mbuf[H];
  float* Kl = (float*)Kl4;
  float* Vl = (float*)Vl4;
  float* Gl = (float*)Gl4;
  int*   xl = (int*)xl4;

  const int b = blockIdx.x;
  const int lane = threadIdx.x;

  // ---- stage tables + token row into LDS ----
  {
    const float4* Kg = (const float4*)Ktab;
    const float4* Vg = (const float4*)Vtab;
    for (int q = lane; q < VOCABN * H / 4; q += 64) { Kl4[q] = Kg[q]; Vl4[q] = Vg[q]; }
    const int4* xg = (const int4*)(x + b * LSEQ);
    for (int q = lane; q < LSEQ / 4; q += 64) xl4[q] = xg[q];
    thl[lane] = nvtab[lane];
  }
  __syncthreads();

  // ---- Gram in LDS: Gl[c2][lane] = khat_lane . khat_c2 (verbatim round 8) ----
  {
    float4 kr[16];
#pragma unroll
    for (int q = 0; q < 16; ++q) kr[q] = Kl4[lane * 16 + q];
    for (int c2 = 0; c2 < VOCABN; ++c2) {
      const float4* kp2 = (const float4*)(Kl + c2 * H);
      float a0 = 0.f, a1 = 0.f, a2 = 0.f, a3 = 0.f;
#pragma unroll
      for (int q = 0; q < 16; ++q) {
        float4 kq = kp2[q];
        a0 = fmaf(kr[q].x, kq.x, a0);
        a1 = fmaf(kr[q].y, kq.y, a1);
        a2 = fmaf(kr[q].z, kq.z, a2);
        a3 = fmaf(kr[q].w, kq.w, a3);
      }
      Gl[c2 * H + lane] = (a0 + a1) + (a2 + a3);
    }
  }
  __syncthreads();

  // ---- residual table in registers: Rq[q] = R[4q+e][lane], init = v (M=0) ----
  float4 Rq[16];
#pragma unroll
  for (int q = 0; q < 16; ++q) {
    Rq[q].x = Vl[(4 * q + 0) * H + lane];
    Rq[q].y = Vl[(4 * q + 1) * H + lane];
    Rq[q].z = Vl[(4 * q + 2) * H + lane];
    Rq[q].w = Vl[(4 * q + 3) * H + lane];
  }

  float4 M4[16];
#pragma unroll
  for (int q = 0; q < 16; ++q) M4[q] = make_float4(0.f, 0.f, 0.f, 0.f);

  int   c   = __builtin_amdgcn_readfirstlane(xl[0]);
  float thr = thl[c];

  for (int t = 0; t < LSEQ; ++t) {
    const int tn = (t + 1 < LSEQ) ? (t + 1) : t;
    int   cn   = xl[tn];                  // prefetch next token
    float thrn = thl[cn & (VOCABN - 1)];  // prefetch next threshold

    const float rv  = extract_rq(Rq, c);  // R[c][lane], all-register
    float nd2 = reduce_to_lane63(rv * rv);
    float nds = sqrtf(__int_as_float(__builtin_amdgcn_readlane(__float_as_int(nd2), 63)));
    float thu = __int_as_float(__builtin_amdgcn_readfirstlane(__float_as_int(thr)));

    if (nds > thu) {
      // accept: delta[lane] = rv. Update R (all tokens) and M (row lane).
      const float4* gp = (const float4*)(Gl + c * H);
      const float4* kp = (const float4*)(Kl + c * H);
#pragma unroll
      for (int q = 0; q < 16; ++q) {
        float4 g4 = gp[q];                // broadcast b128
        Rq[q].x = fmaf(-g4.x, rv, Rq[q].x);
        Rq[q].y = fmaf(-g4.y, rv, Rq[q].y);
        Rq[q].z = fmaf(-g4.z, rv, Rq[q].z);
        Rq[q].w = fmaf(-g4.w, rv, Rq[q].w);
      }
#pragma unroll
      for (int q = 0; q < 16; ++q) {
        float4 k4 = kp[q];                // broadcast b128
        M4[q].x = fmaf(rv, k4.x, M4[q].x);
        M4[q].y = fmaf(rv, k4.y, M4[q].y);
        M4[q].z = fmaf(rv, k4.z, M4[q].z);
        M4[q].w = fmaf(rv, k4.w, M4[q].w);
      }
    }
    c = __builtin_amdgcn_readfirstlane(cn);
    thr = thrn;
  }

  // ---------------- fused readout (verbatim round 8, passed) ----------------
  __syncthreads();
  // M row-major into Kl (M_N[i*H+j]), transposed into Vl (M_T[j*H+i])
  {
    float4* MN = (float4*)(Kl + lane * H);
#pragma unroll
    for (int q = 0; q < 16; ++q) MN[q] = M4[q];
#pragma unroll
    for (int q = 0; q < 16; ++q) {
      Vl[(4 * q + 0) * H + lane] = M4[q].x;
      Vl[(4 * q + 1) * H + lane] = M4[q].y;
      Vl[(4 * q + 2) * H + lane] = M4[q].z;
      Vl[(4 * q + 3) * H + lane] = M4[q].w;
    }
  }
  __syncthreads();

  const int clast = xl[LSEQ - 1];
  hbuf[lane] = Htab[clast * H + lane];
  __syncthreads();

  float qi = 0.f;
  for (int j = 0; j < H; ++j) qi = fmaf(Wq[lane * H + j], hbuf[j], qi);
  qbuf[lane] = qi;
  __syncthreads();

  float qri = 0.f;
  for (int j = 0; j < H; ++j) qri = fmaf(Wr[lane * H + j], qbuf[j], qri);

  // slot norms^2: slot s = column s of M; lane s reads M_N[i*H+s] (conflict-free)
  float n2 = 0.f;
  for (int i2 = 0; i2 < H; ++i2) { float m = Kl[i2 * H + lane]; n2 = fmaf(m, m, n2); }

  // top-8 slots by norm (ties -> smaller index, matching lax.top_k)
  const int KS = 8;
  int idxs[KS];
  float nloc = n2;
#pragma unroll
  for (int k = 0; k < KS; ++k) {
    float v = nloc; int idx = lane;
#pragma unroll
    for (int s = 1; s < 64; s <<= 1) {
      float ov = __shfl_xor(v, s, 64);
      int   oi = __shfl_xor(idx, s, 64);
      if (ov > v || (ov == v && oi < idx)) { v = ov; idx = oi; }
    }
    idxs[k] = idx;
    if (lane == idx) nloc = -1.f;
  }

  // logits + selected slot values (sel[k][lane] = M_T[idx_k*H + lane])
  float sel[KS], lg[KS];
#pragma unroll
  for (int k = 0; k < KS; ++k) {
    float s = Vl[idxs[k] * H + lane];
    sel[k] = s;
    lg[k] = wave_allsum(s * qri) * 0.125f;   // / sqrt(64)
  }
  float lmax = lg[0];
#pragma unroll
  for (int k = 1; k < KS; ++k) lmax = fmaxf(lmax, lg[k]);
  float esum = 0.f, retro = 0.f;
#pragma unroll
  for (int k = 0; k < KS; ++k) {
    float e = expf(lg[k] - lmax);
    esum += e;
    retro = fmaf(e, sel[k], retro);
  }
  retro /= esum;

  // m_ctx = M q  (M rows still in registers; q broadcast from LDS)
  float mc = 0.f;
#pragma unroll
  for (int q2 = 0; q2 < 16; ++q2) {
    mc = fmaf(M4[q2].x, qbuf[4 * q2 + 0], mc);
    mc = fmaf(M4[q2].y, qbuf[4 * q2 + 1], mc);
    mc = fmaf(M4[q2].z, qbuf[4 * q2 + 2], mc);
    mc = fmaf(M4[q2].w, qbuf[4 * q2 + 3], mc);
  }

  float a = 1.f / (1.f + expf(-alpha[0]));
  float mixed = fmaxf(fmaf(a, retro, (1.f - a) * mc), 0.f);
  mbuf[lane] = mixed;
  __syncthreads();

  float oo = bout[lane];
  for (int i2 = 0; i2 < H; ++i2) oo = fmaf(Wout[lane * H + i2], mbuf[i2], oo);
  out[b * VOCABN + lane] = oo;
}

extern "C" void kernel_launch(void* const* d_in, const int* in_sizes, int n_in,
                              void* d_out, int out_size, void* d_ws, size_t ws_size,
                              hipStream_t stream) {
  const int*   x     = (const int*)d_in[0];
  const float* embed = (const float*)d_in[1];
  const float* W1    = (const float*)d_in[2];
  const float* b1    = (const float*)d_in[3];
  const float* W2    = (const float*)d_in[4];
  const float* b2    = (const float*)d_in[5];
  const float* ln_g  = (const float*)d_in[6];
  const float* ln_b  = (const float*)d_in[7];
  const float* Wk    = (const float*)d_in[8];
  const float* Wv    = (const float*)d_in[9];
  const float* Wq    = (const float*)d_in[10];
  const float* Wr    = (const float*)d_in[11];
  const float* alpha = (const float*)d_in[12];
  const float* Wout  = (const float*)d_in[13];
  const float* bout  = (const float*)d_in[14];
  float* out = (float*)d_out;

  const int B = in_sizes[0] / LSEQ;

  float* ws    = (float*)d_ws;
  float* Htab  = ws;          // 4096
  float* Ktab  = ws + 4096;   // 4096
  float* Vtab  = ws + 8192;   // 4096
  float* nvtab = ws + 12288;  // 64   (round-3 proven layout)

  tables_kernel<<<VOCABN, 64, 0, stream>>>(embed, W1, b1, W2, b2, ln_g, ln_b,
                                           Wk, Wv, Htab, Ktab, Vtab, nvtab);
  scan_kernel<<<B, 64, 0, stream>>>(x, Htab, Ktab, Vtab, nvtab,
                                    Wq, Wr, alpha, Wout, bout, out);
}

// Round 10
// 655.527 us; speedup vs baseline: 2.1877x; 1.6966x over previous
//
#include <hip/hip_runtime.h>
#include <math.h>

#define H 64
#define VOCABN 64
#define LSEQ 2048
#define LN_EPS 1e-5f

// ---------- generic DPP add helper ----------
template <int CTRL>
__device__ __forceinline__ float dpp_add(float x) {
  return x + __int_as_float(__builtin_amdgcn_update_dpp(
      0, __float_as_int(x), CTRL, 0xF, 0xF, true));
}

// all-lane sum with broadcast result (tables / readout only)
__device__ __forceinline__ float wave_allsum(float x) {
  x = dpp_add<0xB1>(x);   // quad_perm [1,0,3,2]
  x = dpp_add<0x4E>(x);   // quad_perm [2,3,0,1]
  x = dpp_add<0x141>(x);  // row_half_mirror
  x = dpp_add<0x140>(x);  // row_mirror
  x += __shfl_xor(x, 16, 64);
  x += __shfl_xor(x, 32, 64);
  return x;
}

// all-VALU wave64 reduction: lane 63 holds the total (rounds 3/7/8 validated)
__device__ __forceinline__ float reduce_to_lane63(float x) {
  x = dpp_add<0x111>(x);  // row_shr:1
  x = dpp_add<0x112>(x);  // row_shr:2
  x = dpp_add<0x114>(x);  // row_shr:4
  x = dpp_add<0x118>(x);  // row_shr:8
  x = dpp_add<0x142>(x);  // row_bcast:15
  x = dpp_add<0x143>(x);  // row_bcast:31
  return x;
}

// ---------------- Kernel A: per-token tables (verbatim rounds 7-9, passed) ----------------
__global__ __launch_bounds__(64) void tables_kernel(
    const float* __restrict__ embed, const float* __restrict__ W1, const float* __restrict__ b1,
    const float* __restrict__ W2, const float* __restrict__ b2,
    const float* __restrict__ ln_g, const float* __restrict__ ln_b,
    const float* __restrict__ Wk, const float* __restrict__ Wv,
    float* __restrict__ Htab, float* __restrict__ Ktab, float* __restrict__ Vtab,
    float* __restrict__ nvtab)
{
  __shared__ float hs[H];
  __shared__ float ff1[2 * H];
  __shared__ float lns[H];
  const int c = blockIdx.x;
  const int i = threadIdx.x;

  float e = embed[c * H + i];
  hs[i] = e;
  __syncthreads();

  float r1 = b1[i], r2 = b1[i + H];
  for (int j = 0; j < H; ++j) {
    float hj = hs[j];
    r1 = fmaf(W1[i * H + j], hj, r1);
    r2 = fmaf(W1[(i + H) * H + j], hj, r2);
  }
  ff1[i]     = fmaxf(r1, 0.f);
  ff1[i + H] = fmaxf(r2, 0.f);
  __syncthreads();

  float o = b2[i];
  for (int m = 0; m < 2 * H; ++m) o = fmaf(W2[i * 2 * H + m], ff1[m], o);
  float y = e + o;

  float mu  = wave_allsum(y) * (1.f / H);
  float d   = y - mu;
  float var = wave_allsum(d * d) * (1.f / H);
  float ln  = d * (1.f / sqrtf(var + LN_EPS)) * ln_g[i] + ln_b[i];
  lns[i] = ln;
  __syncthreads();
  Htab[c * H + i] = ln;

  float k = 0.f, v = 0.f;
  for (int j = 0; j < H; ++j) {
    float lj = lns[j];
    k = fmaf(Wk[i * H + j], lj, k);
    v = fmaf(Wv[i * H + j], lj, v);
  }
  float nk = sqrtf(wave_allsum(k * k));
  Ktab[c * H + i] = k / fmaxf(nk, 1e-12f);
  Vtab[c * H + i] = v;
  float nv = sqrtf(wave_allsum(v * v));
  if (i == 0) nvtab[c] = 0.4f * nv;   // gate threshold, sqrt domain (round-3 semantics)
}

// ---------------- Kernel B: 4-wave cooperative residual scan + fused readout ----------------
// One block (4 waves) per batch element. R[c][i] in LDS; M rows in registers,
// maintained redundantly and bit-identically by each wave (same broadcasts, same delta).
// Per step: stride-1 prefetch + DPP reduce + sqrt gate (block-uniform branch).
// Per accept: R-update split 16 rows/wave (LDS pipe) + M 64 FMA (VALU pipe), 2 barriers.
// Numerics: incremental-R gates/deltas proven faithful by rounds 4==5; sqrt compare +
// in-LDS Gram are the rounds-7/8-validated choices.
__global__ __launch_bounds__(256, 1) void scan_kernel(
    const int* __restrict__ x, const float* __restrict__ Htab,
    const float* __restrict__ Ktab, const float* __restrict__ Vtab,
    const float* __restrict__ nvtab,
    const float* __restrict__ Wq, const float* __restrict__ Wr,
    const float* __restrict__ alpha, const float* __restrict__ Wout,
    const float* __restrict__ bout, float* __restrict__ out)
{
  __shared__ float4 Kl4[VOCABN * H / 4];   // khat [c][j]; reused as M_N in readout
  __shared__ float4 Vl4[VOCABN * H / 4];   // v [c][i];   reused as M_T in readout
  __shared__ float4 Gl4[VOCABN * H / 4];   // Gram [c][cc]
  __shared__ float4 Rl4[VOCABN * H / 4];   // residual [c][i]
  __shared__ int4   xl4[LSEQ / 4];
  __shared__ float  thl[VOCABN];           // 0.4*||v||
  __shared__ float  hbuf[H];
  __shared__ float  qbuf[H];
  __shared__ float  mbuf[H];
  float* Kl = (float*)Kl4;
  float* Vl = (float*)Vl4;
  float* Gl = (float*)Gl4;
  float* Rl = (float*)Rl4;
  int*   xl = (int*)xl4;

  const int b    = blockIdx.x;
  const int tid  = threadIdx.x;
  const int lane = tid & 63;
  const int wid  = tid >> 6;

  // ---- stage tables + token row into LDS (256 threads) ----
  {
    const float4* Kg = (const float4*)Ktab;
    const float4* Vg = (const float4*)Vtab;
    for (int q = tid; q < VOCABN * H / 4; q += 256) {
      float4 vq = Vg[q];
      Kl4[q] = Kg[q]; Vl4[q] = vq; Rl4[q] = vq;   // R init = v (M = 0)
    }
    const int4* xg = (const int4*)(x + b * LSEQ);
    for (int q = tid; q < LSEQ / 4; q += 256) xl4[q] = xg[q];
    if (tid < VOCABN) thl[tid] = nvtab[tid];
  }
  __syncthreads();

  // ---- Gram in LDS, rows split across waves: Gl[c2][lane] = khat_lane . khat_c2 ----
  {
    float4 kr[16];
#pragma unroll
    for (int q = 0; q < 16; ++q) kr[q] = Kl4[lane * 16 + q];
    for (int r = 0; r < 16; ++r) {
      const int c2 = wid * 16 + r;
      const float4* kp2 = (const float4*)(Kl + c2 * H);
      float a0 = 0.f, a1 = 0.f, a2 = 0.f, a3 = 0.f;
#pragma unroll
      for (int q = 0; q < 16; ++q) {
        float4 kq = kp2[q];
        a0 = fmaf(kr[q].x, kq.x, a0);
        a1 = fmaf(kr[q].y, kq.y, a1);
        a2 = fmaf(kr[q].z, kq.z, a2);
        a3 = fmaf(kr[q].w, kq.w, a3);
      }
      Gl[c2 * H + lane] = (a0 + a1) + (a2 + a3);
    }
  }
  __syncthreads();

  float4 M4[16];
#pragma unroll
  for (int q = 0; q < 16; ++q) M4[q] = make_float4(0.f, 0.f, 0.f, 0.f);

  int   c   = xl[0];
  int   cn  = xl[1];
  float rv  = Rl[c * H + lane];
  float thr = thl[c];

  for (int t = 0; t < LSEQ; ++t) {
    float rvn  = Rl[cn * H + lane];          // speculative stride-1 prefetch
    float thrn = thl[cn];
    const int cn2 = (t + 2 < LSEQ) ? xl[t + 2] : 0;

    float nd2 = reduce_to_lane63(rv * rv);
    float nds = sqrtf(__int_as_float(__builtin_amdgcn_readlane(__float_as_int(nd2), 63)));
    float thu = __int_as_float(__builtin_amdgcn_readfirstlane(__float_as_int(thr)));

    if (nds > thu) {                         // block-uniform (identical data per wave)
      __syncthreads();                       // all waves' reads of R complete
      const float delta = rv;
      // R[cc][lane] -= G[c][cc] * delta ; 16 rows per wave
#pragma unroll
      for (int r = 0; r < 16; ++r) {
        const int cc = wid * 16 + r;
        float g = Gl[c * H + cc];            // per-wave broadcast
        Rl[cc * H + lane] = fmaf(-g, delta, Rl[cc * H + lane]);
      }
      // M row lane += delta * khat_c  (redundant per wave, bit-identical)
      const float4* kp = (const float4*)(Kl + c * H);
#pragma unroll
      for (int q = 0; q < 16; ++q) {
        float4 k4 = kp[q];
        M4[q].x = fmaf(delta, k4.x, M4[q].x);
        M4[q].y = fmaf(delta, k4.y, M4[q].y);
        M4[q].z = fmaf(delta, k4.z, M4[q].z);
        M4[q].w = fmaf(delta, k4.w, M4[q].w);
      }
      __syncthreads();                       // updates visible to all waves
      rvn = Rl[cn * H + lane];               // reload (speculative was stale)
    }
    rv = rvn; thr = thrn; c = cn; cn = cn2;
  }

  // ---------------- fused readout: wave 0 only (has full M); no barriers needed inside ----------------
  __syncthreads();
  if (wid == 0) {
    // M row-major into Kl (M_N[i*H+j]), transposed into Vl (M_T[j*H+i])
    float4* MN = (float4*)(Kl + lane * H);
#pragma unroll
    for (int q = 0; q < 16; ++q) MN[q] = M4[q];
#pragma unroll
    for (int q = 0; q < 16; ++q) {
      Vl[(4 * q + 0) * H + lane] = M4[q].x;
      Vl[(4 * q + 1) * H + lane] = M4[q].y;
      Vl[(4 * q + 2) * H + lane] = M4[q].z;
      Vl[(4 * q + 3) * H + lane] = M4[q].w;
    }

    const int clast = xl[LSEQ - 1];
    hbuf[lane] = Htab[clast * H + lane];

    float qi = 0.f;
    for (int j = 0; j < H; ++j) qi = fmaf(Wq[lane * H + j], hbuf[j], qi);
    qbuf[lane] = qi;

    float qri = 0.f;
    for (int j = 0; j < H; ++j) qri = fmaf(Wr[lane * H + j], qbuf[j], qri);

    // slot norms^2: lane s reads M_N[i*H+s] (conflict-free)
    float n2 = 0.f;
    for (int i2 = 0; i2 < H; ++i2) { float m = Kl[i2 * H + lane]; n2 = fmaf(m, m, n2); }

    // top-8 slots by norm (ties -> smaller index)
    const int KS = 8;
    int idxs[KS];
    float nloc = n2;
#pragma unroll
    for (int k = 0; k < KS; ++k) {
      float v = nloc; int idx = lane;
#pragma unroll
      for (int s = 1; s < 64; s <<= 1) {
        float ov = __shfl_xor(v, s, 64);
        int   oi = __shfl_xor(idx, s, 64);
        if (ov > v || (ov == v && oi < idx)) { v = ov; idx = oi; }
      }
      idxs[k] = idx;
      if (lane == idx) nloc = -1.f;
    }

    float sel[KS], lg[KS];
#pragma unroll
    for (int k = 0; k < KS; ++k) {
      float s = Vl[idxs[k] * H + lane];
      sel[k] = s;
      lg[k] = wave_allsum(s * qri) * 0.125f;   // / sqrt(64)
    }
    float lmax = lg[0];
#pragma unroll
    for (int k = 1; k < KS; ++k) lmax = fmaxf(lmax, lg[k]);
    float esum = 0.f, retro = 0.f;
#pragma unroll
    for (int k = 0; k < KS; ++k) {
      float e = expf(lg[k] - lmax);
      esum += e;
      retro = fmaf(e, sel[k], retro);
    }
    retro /= esum;

    // m_ctx = M q (M rows in registers; q from qbuf)
    float mc = 0.f;
#pragma unroll
    for (int q2 = 0; q2 < 16; ++q2) {
      mc = fmaf(M4[q2].x, qbuf[4 * q2 + 0], mc);
      mc = fmaf(M4[q2].y, qbuf[4 * q2 + 1], mc);
      mc = fmaf(M4[q2].z, qbuf[4 * q2 + 2], mc);
      mc = fmaf(M4[q2].w, qbuf[4 * q2 + 3], mc);
    }

    float a = 1.f / (1.f + expf(-alpha[0]));
    float mixed = fmaxf(fmaf(a, retro, (1.f - a) * mc), 0.f);
    mbuf[lane] = mixed;

    float oo = bout[lane];
    for (int i2 = 0; i2 < H; ++i2) oo = fmaf(Wout[lane * H + i2], mbuf[i2], oo);
    out[b * VOCABN + lane] = oo;
  }
}

extern "C" void kernel_launch(void* const* d_in, const int* in_sizes, int n_in,
                              void* d_out, int out_size, void* d_ws, size_t ws_size,
                              hipStream_t stream) {
  const int*   x     = (const int*)d_in[0];
  const float* embed = (const float*)d_in[1];
  const float* W1    = (const float*)d_in[2];
  const float* b1    = (const float*)d_in[3];
  const float* W2    = (const float*)d_in[4];
  const float* b2    = (const float*)d_in[5];
  const float* ln_g  = (const float*)d_in[6];
  const float* ln_b  = (const float*)d_in[7];
  const float* Wk    = (const float*)d_in[8];
  const float* Wv    = (const float*)d_in[9];
  const float* Wq    = (const float*)d_in[10];
  const float* Wr    = (const float*)d_in[11];
  const float* alpha = (const float*)d_in[12];
  const float* Wout  = (const float*)d_in[13];
  const float* bout  = (const float*)d_in[14];
  float* out = (float*)d_out;

  const int B = in_sizes[0] / LSEQ;

  float* ws    = (float*)d_ws;
  float* Htab  = ws;          // 4096
  float* Ktab  = ws + 4096;   // 4096
  float* Vtab  = ws + 8192;   // 4096
  float* nvtab = ws + 12288;  // 64   (round-3 proven layout)

  tables_kernel<<<VOCABN, 64, 0, stream>>>(embed, W1, b1, W2, b2, ln_g, ln_b,
                                           Wk, Wv, Htab, Ktab, Vtab, nvtab);
  scan_kernel<<<B, 256, 0, stream>>>(x, Htab, Ktab, Vtab, nvtab,
                                     Wq, Wr, alpha, Wout, bout, out);
}